// Round 5
// baseline (316.740 us; speedup 1.0000x reference)
//
#include <hip/hip_runtime.h>
#include <stdint.h>

typedef __attribute__((ext_vector_type(8))) short short8;
typedef __attribute__((ext_vector_type(2))) short short2_t;
typedef __attribute__((ext_vector_type(4))) float floatx4;

#define TT 128
#define DD 128

// Workgroup barrier that waits ONLY on LDS ops (lgkmcnt), leaving global
// loads/stores in flight (__syncthreads would drain vmcnt(0) -> puts an HBM
// round-trip on every timestep's critical path).
#define BARRIER_LDS() asm volatile("s_waitcnt lgkmcnt(0)\n\ts_barrier" ::: "memory")

__device__ __forceinline__ short f2bf(float f) {
  union { float f; uint32_t u; } v; v.f = f;
  uint32_t u = v.u;
  u += 0x7fffu + ((u >> 16) & 1u);   // round-to-nearest-even
  return (short)(u >> 16);
}

__device__ __forceinline__ float sigf(float x) {
  return __builtin_amdgcn_rcpf(1.f + __expf(-x));
}
__device__ __forceinline__ float tanhf_(float x) {
  return 2.f * __builtin_amdgcn_rcpf(1.f + __expf(-2.f * x)) - 1.f;
}

// Transpose+bf16-convert all four weight matrices.
// src fp32 [K][256] (Keras layout) -> dst bf16 [256][K]
__global__ void wtrans_all(const float* __restrict__ W1, const float* __restrict__ U1,
                           const float* __restrict__ W2, const float* __restrict__ U2,
                           short* __restrict__ w1t, short* __restrict__ u1t,
                           short* __restrict__ w2t, short* __restrict__ u2t) {
  int n = blockIdx.x;   // gate column 0..255
  int k = threadIdx.x;  // 0..127
  w1t[n * 128 + k] = f2bf(W1[k * 256 + n]);
  if (k < 64) {
    u1t[n * 64 + k] = f2bf(U1[k * 256 + n]);
    w2t[n * 64 + k] = f2bf(W2[k * 256 + n]);
    u2t[n * 64 + k] = f2bf(U2[k * 256 + n]);
  }
}

// 512 blocks (2/CU) x 4 waves, 4 batch rows per block.
// Batch row r occupies M-rows 4r..4r+3 -> C-layout reg 0 of quad q is the
// real (row=q) element: elementwise is 1 elem/lane. Wave w owns hidden cols
// 16w..16w+15; all weights in registers.
// ONE lgkmcnt-only barrier per timestep; hb1/hb2/xbuf parity double-buffered
// (t&1) so producer->consumer pairs are always separated by >=1 barrier and
// buffer reuse by >=2. h2(t-1) is read after barrier(t) from parity 1-p.
// LDS strides: hb 80 elems, xbuf 144 elems -> all accesses <=2-way banked.
// MFMA 16x16x32 bf16 layouts (verified m89/m120):
//   A-frag: A[m = lane&15][k = (lane>>4)*8 + j] (+32/kstep)
//   B-frag: B[k = (lane>>4)*8 + j][n = lane&15]
//   C/D   : col = lane&15, row = (lane>>4)*4 + reg
__global__ __launch_bounds__(256, 2) void lstm_fused(
    const float* __restrict__ x,
    const short* __restrict__ w1t, const short* __restrict__ u1t,
    const short* __restrict__ w2t, const short* __restrict__ u2t,
    const float* __restrict__ b1, const float* __restrict__ b2,
    float* __restrict__ out) {
  __shared__ short hb1[2][4 * 80];
  __shared__ short hb2[2][4 * 80];
  __shared__ short xbuf[2][4 * 144];

  const int tid = threadIdx.x;
  const int w = tid >> 6;          // wave id -> hidden-col slice
  const int lane = tid & 63;
  const int mrow = lane & 15;
  const int quad = lane >> 4;
  const int rowbase = blockIdx.x * 4;
  const int colw = w * 16 + mrow;
  const int br_a = mrow >> 2;      // A-frag batch row (4x duplicated over mrow&3)

  // ---- weight slice -> registers ----
  short8 w1r[4][4], u1r[4][2], w2r[4][2], u2r[4][2];
#pragma unroll
  for (int g = 0; g < 4; ++g) {
    const int n = g * 4 + w;  // gate tile (g=0:i 1:f 2:g 3:o), cols 16w..16w+15
#pragma unroll
    for (int s = 0; s < 4; ++s)
      w1r[g][s] = *(const short8*)(w1t + n * 2048 + mrow * 128 + quad * 8 + s * 32);
#pragma unroll
    for (int s = 0; s < 2; ++s) {
      u1r[g][s] = *(const short8*)(u1t + n * 1024 + mrow * 64 + quad * 8 + s * 32);
      w2r[g][s] = *(const short8*)(w2t + n * 1024 + mrow * 64 + quad * 8 + s * 32);
      u2r[g][s] = *(const short8*)(u2t + n * 1024 + mrow * 64 + quad * 8 + s * 32);
    }
  }
  float bias1[4], bias2[4];
#pragma unroll
  for (int g = 0; g < 4; ++g) {
    bias1[g] = b1[g * 64 + colw];
    bias2[g] = b2[g * 64 + colw];
  }

  // ---- x staging mapping: thread -> (row = tid>>6, 2 floats) ----
  const int xr = tid >> 6;
  const int xc = (tid & 63) * 2;
  const float* xload = x + (size_t)(rowbase + xr) * (TT * DD) + xc;

  // ---- prologue: zero hb2, stage x(0) into xbuf[1], read frags ----
  {
    short* z = (short*)hb2;
    for (int i = tid; i < 2 * 4 * 80; i += 256) z[i] = 0;
    float a0 = xload[0], a1 = xload[1];
    *(short2_t*)&xbuf[1][xr * 144 + xc] = short2_t{f2bf(a0), f2bf(a1)};
  }
  BARRIER_LDS();
  short8 xf[4];
#pragma unroll
  for (int s = 0; s < 4; ++s)
    xf[s] = *(const short8*)&xbuf[1][br_a * 144 + (quad + 4 * s) * 8];
  float xr0 = xload[DD], xr1 = xload[DD + 1];  // x(1)

  short8 h1f[2], h2f[2];
#pragma unroll
  for (int s = 0; s < 2; ++s)
#pragma unroll
    for (int j = 0; j < 8; ++j) { h1f[s][j] = 0; h2f[s][j] = 0; }
  float c1 = 0.f, c2 = 0.f;

#pragma unroll 1
  for (int t = 0; t < TT; ++t) {
    const int p = t & 1;

    // ---- layer 1 MFMA: z1 = x_t @ W1 + h1(t-1) @ U1 ----
    floatx4 acc[4];
#pragma unroll
    for (int g = 0; g < 4; ++g) acc[g] = floatx4{0.f, 0.f, 0.f, 0.f};
#pragma unroll
    for (int g = 0; g < 4; ++g) {
#pragma unroll
      for (int s = 0; s < 4; ++s)
        acc[g] = __builtin_amdgcn_mfma_f32_16x16x32_bf16(xf[s], w1r[g][s], acc[g], 0, 0, 0);
#pragma unroll
      for (int s = 0; s < 2; ++s)
        acc[g] = __builtin_amdgcn_mfma_f32_16x16x32_bf16(h1f[s], u1r[g][s], acc[g], 0, 0, 0);
    }

    // ---- stage x(t+1) into xbuf[p]; prefetch x(t+2) ----
    *(short2_t*)&xbuf[p][xr * 144 + xc] = short2_t{f2bf(xr0), f2bf(xr1)};
    {
      int tn = (t + 2 < TT) ? t + 2 : TT - 1;
      xr0 = xload[(size_t)tn * DD];
      xr1 = xload[(size_t)tn * DD + 1];
    }

    // ---- layer 1 elementwise (1 elem/lane: batch row = quad, col = colw) ----
    {
      float ig = sigf(acc[0][0] + bias1[0]);
      float fg = sigf(acc[1][0] + bias1[1]);
      float gg = tanhf_(acc[2][0] + bias1[2]);
      float og = sigf(acc[3][0] + bias1[3]);
      float c = fg * c1 + ig * gg;
      c1 = c;
      float h = og * tanhf_(c);
      hb1[p][quad * 80 + colw] = f2bf(h);
    }

    BARRIER_LDS();  // the ONLY barrier per timestep

    // h1(t), x(t+1), h2(t-1) — all produced before this barrier
#pragma unroll
    for (int s = 0; s < 2; ++s) {
      h1f[s] = *(const short8*)&hb1[p][br_a * 80 + (quad + 4 * s) * 8];
      h2f[s] = *(const short8*)&hb2[1 - p][br_a * 80 + (quad + 4 * s) * 8];
    }
#pragma unroll
    for (int s = 0; s < 4; ++s)
      xf[s] = *(const short8*)&xbuf[p][br_a * 144 + (quad + 4 * s) * 8];

    // ---- layer 2 MFMA: z2 = h1(t) @ W2 + h2(t-1) @ U2 ----
    floatx4 bcc[4];
#pragma unroll
    for (int g = 0; g < 4; ++g) bcc[g] = floatx4{0.f, 0.f, 0.f, 0.f};
#pragma unroll
    for (int g = 0; g < 4; ++g) {
#pragma unroll
      for (int s = 0; s < 2; ++s)
        bcc[g] = __builtin_amdgcn_mfma_f32_16x16x32_bf16(h1f[s], w2r[g][s], bcc[g], 0, 0, 0);
#pragma unroll
      for (int s = 0; s < 2; ++s)
        bcc[g] = __builtin_amdgcn_mfma_f32_16x16x32_bf16(h2f[s], u2r[g][s], bcc[g], 0, 0, 0);
    }

    // ---- layer 2 elementwise (sigmoid activation) + h2 publish + output ----
    {
      float ig = sigf(bcc[0][0] + bias2[0]);
      float fg = sigf(bcc[1][0] + bias2[1]);
      float gg = sigf(bcc[2][0] + bias2[2]);
      float og = sigf(bcc[3][0] + bias2[3]);
      float c = fg * c2 + ig * gg;
      c2 = c;
      float h = og * sigf(c);
      hb2[p][quad * 80 + colw] = f2bf(h);  // read at t+1, after barrier(t+1)
      out[(size_t)(rowbase + quad) * 8192 + t * 64 + colw] = h;
    }
  }
}

extern "C" void kernel_launch(void* const* d_in, const int* in_sizes, int n_in,
                              void* d_out, int out_size, void* d_ws, size_t ws_size,
                              hipStream_t stream) {
  const float* x  = (const float*)d_in[0];
  const float* W1 = (const float*)d_in[1];
  const float* U1 = (const float*)d_in[2];
  const float* b1 = (const float*)d_in[3];
  const float* W2 = (const float*)d_in[4];
  const float* U2 = (const float*)d_in[5];
  const float* b2 = (const float*)d_in[6];
  float* out = (float*)d_out;

  short* w1t = (short*)d_ws;        // [256][128] bf16
  short* u1t = w1t + 32768;         // [256][64]
  short* w2t = u1t + 16384;         // [256][64]
  short* u2t = w2t + 16384;         // [256][64]

  hipLaunchKernelGGL(wtrans_all, dim3(256), dim3(128), 0, stream,
                     W1, U1, W2, U2, w1t, u1t, w2t, u2t);
  hipLaunchKernelGGL(lstm_fused, dim3(512), dim3(256), 0, stream,
                     x, w1t, u1t, w2t, u2t, b1, b2, out);
}

// Round 6
// 285.974 us; speedup vs baseline: 1.1076x; 1.1076x over previous
//
#include <hip/hip_runtime.h>
#include <stdint.h>

typedef __attribute__((ext_vector_type(8))) short short8;
typedef __attribute__((ext_vector_type(4))) short short4_t;
typedef __attribute__((ext_vector_type(4))) float floatx4;

#define TT 128
#define DD 128

// Barrier waiting only on LDS ops: global loads/stores stay in flight.
#define BARRIER_LDS() asm volatile("s_waitcnt lgkmcnt(0)\n\ts_barrier" ::: "memory")

__device__ __forceinline__ short f2bf(float f) {
  union { float f; uint32_t u; } v; v.f = f;
  uint32_t u = v.u;
  u += 0x7fffu + ((u >> 16) & 1u);   // round-to-nearest-even
  return (short)(u >> 16);
}

__device__ __forceinline__ float sigf(float x) {
  return __builtin_amdgcn_rcpf(1.f + __expf(-x));
}
__device__ __forceinline__ float tanhf_(float x) {
  return 2.f * __builtin_amdgcn_rcpf(1.f + __expf(-2.f * x)) - 1.f;
}

// Transpose+bf16-convert all four weight matrices.
// src fp32 [K][256] (Keras layout) -> dst bf16 [256][K]
__global__ void wtrans_all(const float* __restrict__ W1, const float* __restrict__ U1,
                           const float* __restrict__ W2, const float* __restrict__ U2,
                           short* __restrict__ w1t, short* __restrict__ u1t,
                           short* __restrict__ w2t, short* __restrict__ u2t) {
  int n = blockIdx.x;   // gate column 0..255
  int k = threadIdx.x;  // 0..127
  w1t[n * 128 + k] = f2bf(W1[k * 256 + n]);
  if (k < 64) {
    u1t[n * 64 + k] = f2bf(U1[k * 256 + n]);
    w2t[n * 64 + k] = f2bf(W2[k * 256 + n]);
    u2t[n * 64 + k] = f2bf(U2[k * 256 + n]);
  }
}

// 256 blocks x 8 waves (512 thr), 8 batch rows/block. HETEROGENEOUS waves:
//   waves 0-3: layer 1 only (gate-split over hidden cols, W1/U1 in regs, 24 MFMA)
//   waves 4-7: layer 2 only (W2/U2 in regs, 16 MFMA), lagging ONE timestep,
//              plus x(t+1) fp32->bf16 staging (they're the lighter waves).
// Each SIMD hosts one L1-wave + one L2-wave with complementary pipe phases
// (L1 elementwise overlaps L2 MFMA and vice versa) -> hides chain latency
// that rounds 3-5's homogeneous waves could not.
// Batch rows at M-rows {0,1,4,5,8,9,12,13} (br_a = 2*(mrow>>2)+(mrow&1)):
// C-regs 0,1 of quad q = real rows 2q,2q+1 -> elementwise 2 elems/lane.
// One lgkm-only barrier/iteration; hb1/hb2/xbuf parity double-buffered.
// i runs 0..TT: L1 computes t=i (skip i=TT), L2 computes t=i-1 (skip i=0).
// LDS strides: hb 80 elems, xbuf 144 -> every access <=2-way banked (free, m136).
// MFMA 16x16x32 bf16 layouts (verified m89/m120):
//   A-frag: A[m=lane&15][k=(lane>>4)*8+j] (+32/kstep)
//   B-frag: B[k=(lane>>4)*8+j][n=lane&15]
//   C/D   : col=lane&15, row=(lane>>4)*4+reg
__global__ __launch_bounds__(512, 2) void lstm_fused(
    const float* __restrict__ x,
    const short* __restrict__ w1t, const short* __restrict__ u1t,
    const short* __restrict__ w2t, const short* __restrict__ u2t,
    const float* __restrict__ b1, const float* __restrict__ b2,
    float* __restrict__ out) {
  __shared__ short hb1[2][8 * 80];
  __shared__ short hb2[2][8 * 80];
  __shared__ short xbuf[2][8 * 144];

  const int tid = threadIdx.x;
  const int w = tid >> 6;
  const bool isL1 = (w < 4);
  const int wg = w & 3;            // gate-column slice within the layer group
  const int lane = tid & 63;
  const int mrow = lane & 15;
  const int quad = lane >> 4;
  const int rowbase = blockIdx.x * 8;
  const int colw = wg * 16 + mrow;
  const int br_a = 2 * (mrow >> 2) + (mrow & 1);  // A-frag batch row (2x dup)

  // ---- weight slices -> registers ----
  // L1: wA[g][0..3]=W1 Ksteps, uA[g][0..1]=U1.
  // L2: wA[g][0..1]=W2, wA[g][2..3]=U2 (uA unused on this path).
  short8 wA[4][4], uA[4][2];
  float bias[4];
  if (isL1) {
#pragma unroll
    for (int g = 0; g < 4; ++g) {
      const int n = g * 4 + wg;
#pragma unroll
      for (int s = 0; s < 4; ++s)
        wA[g][s] = *(const short8*)(w1t + n * 2048 + mrow * 128 + quad * 8 + s * 32);
#pragma unroll
      for (int s = 0; s < 2; ++s)
        uA[g][s] = *(const short8*)(u1t + n * 1024 + mrow * 64 + quad * 8 + s * 32);
      bias[g] = b1[g * 64 + colw];
    }
  } else {
#pragma unroll
    for (int g = 0; g < 4; ++g) {
      const int n = g * 4 + wg;
#pragma unroll
      for (int s = 0; s < 2; ++s) {
        wA[g][s]     = *(const short8*)(w2t + n * 1024 + mrow * 64 + quad * 8 + s * 32);
        wA[g][2 + s] = *(const short8*)(u2t + n * 1024 + mrow * 64 + quad * 8 + s * 32);
      }
      bias[g] = b2[g * 64 + colw];
    }
  }

  // ---- x staging (L2 waves): 256 threads x 4 consecutive floats ----
  const int tid2 = tid & 255;
  const int sxr = tid2 >> 5;          // batch row 0..7
  const int sxc = (tid2 & 31) * 4;    // 4-float group in D=128
  const float* xload = x + (size_t)(rowbase + sxr) * (TT * DD) + sxc;

  // h1f: h1(t-1) A-frags (both groups). xh: L1 = x(t) A-frags; L2 = h2(t-2) A-frags.
  short8 h1f[2], xh[4];
#pragma unroll
  for (int s = 0; s < 2; ++s)
#pragma unroll
    for (int j = 0; j < 8; ++j) h1f[s][j] = 0;
#pragma unroll
  for (int s = 0; s < 4; ++s)
#pragma unroll
    for (int j = 0; j < 8; ++j) xh[s][j] = 0;
  float cc[2] = {0.f, 0.f};
  floatx4 xnext;

  // ---- prologue: zero hb2 (h2(-1)=0 read at i=0), stage x(0), prefetch x(1) ----
  for (int idx = tid; idx < 2 * 8 * 80; idx += 512) ((short*)hb2)[idx] = 0;
  if (!isL1) {
    floatx4 x0 = *(const floatx4*)xload;
    short4_t v;
#pragma unroll
    for (int j = 0; j < 4; ++j) v[j] = f2bf(x0[j]);
    *(short4_t*)&xbuf[0][sxr * 144 + sxc] = v;
    xnext = *(const floatx4*)(xload + DD);
  }
  BARRIER_LDS();
  if (isL1) {
#pragma unroll
    for (int s = 0; s < 4; ++s)
      xh[s] = *(const short8*)&xbuf[0][br_a * 144 + (quad + 4 * s) * 8];
  }

  float* outp = out + (size_t)rowbase * 8192 + colw;  // L2 store base

#pragma unroll 1
  for (int i = 0; i <= TT; ++i) {
    const int p = i & 1;

    if (isL1) {
      if (i < TT) {
        // z1(i) = x(i) @ W1 + h1(i-1) @ U1
        floatx4 acc[4];
#pragma unroll
        for (int g = 0; g < 4; ++g) acc[g] = floatx4{0.f, 0.f, 0.f, 0.f};
#pragma unroll
        for (int g = 0; g < 4; ++g) {
#pragma unroll
          for (int s = 0; s < 4; ++s)
            acc[g] = __builtin_amdgcn_mfma_f32_16x16x32_bf16(xh[s], wA[g][s], acc[g], 0, 0, 0);
#pragma unroll
          for (int s = 0; s < 2; ++s)
            acc[g] = __builtin_amdgcn_mfma_f32_16x16x32_bf16(h1f[s], uA[g][s], acc[g], 0, 0, 0);
        }
#pragma unroll
        for (int r = 0; r < 2; ++r) {
          float ig = sigf(acc[0][r] + bias[0]);
          float fg = sigf(acc[1][r] + bias[1]);
          float gg = tanhf_(acc[2][r] + bias[2]);
          float og = sigf(acc[3][r] + bias[3]);
          float c = fg * cc[r] + ig * gg;
          cc[r] = c;
          float h = og * tanhf_(c);
          hb1[p][(2 * quad + r) * 80 + colw] = f2bf(h);
        }
      }
    } else {
      // stage x(i+1) -> xbuf[1-p]; prefetch x(min(i+2,TT-1))
      {
        short4_t v;
#pragma unroll
        for (int j = 0; j < 4; ++j) v[j] = f2bf(xnext[j]);
        *(short4_t*)&xbuf[1 - p][sxr * 144 + sxc] = v;
        int tn = (i + 2 < TT) ? i + 2 : TT - 1;
        xnext = *(const floatx4*)(xload + (size_t)tn * DD);
      }
      if (i >= 1) {
        // z2(i-1) = h1(i-1) @ W2 + h2(i-2) @ U2
        floatx4 acc[4];
#pragma unroll
        for (int g = 0; g < 4; ++g) acc[g] = floatx4{0.f, 0.f, 0.f, 0.f};
#pragma unroll
        for (int g = 0; g < 4; ++g) {
#pragma unroll
          for (int s = 0; s < 2; ++s)
            acc[g] = __builtin_amdgcn_mfma_f32_16x16x32_bf16(h1f[s], wA[g][s], acc[g], 0, 0, 0);
#pragma unroll
          for (int s = 0; s < 2; ++s)
            acc[g] = __builtin_amdgcn_mfma_f32_16x16x32_bf16(xh[s], wA[g][2 + s], acc[g], 0, 0, 0);
        }
#pragma unroll
        for (int r = 0; r < 2; ++r) {
          float ig = sigf(acc[0][r] + bias[0]);
          float fg = sigf(acc[1][r] + bias[1]);
          float gg = sigf(acc[2][r] + bias[2]);
          float og = sigf(acc[3][r] + bias[3]);
          float c = fg * cc[r] + ig * gg;
          cc[r] = c;
          float h = og * sigf(c);
          hb2[p][(2 * quad + r) * 80 + colw] = f2bf(h);
          outp[(size_t)(2 * quad + r) * 8192 + (i - 1) * 64] = h;
        }
      }
    }

    BARRIER_LDS();  // single barrier per iteration

    if (i < TT) {
      if (isL1) {
#pragma unroll
        for (int s = 0; s < 2; ++s)
          h1f[s] = *(const short8*)&hb1[p][br_a * 80 + (quad + 4 * s) * 8];
#pragma unroll
        for (int s = 0; s < 4; ++s)
          xh[s] = *(const short8*)&xbuf[1 - p][br_a * 144 + (quad + 4 * s) * 8];
      } else {
#pragma unroll
        for (int s = 0; s < 2; ++s) {
          h1f[s] = *(const short8*)&hb1[p][br_a * 80 + (quad + 4 * s) * 8];
          xh[s]  = *(const short8*)&hb2[p][br_a * 80 + (quad + 4 * s) * 8];
        }
      }
    }
  }
}

extern "C" void kernel_launch(void* const* d_in, const int* in_sizes, int n_in,
                              void* d_out, int out_size, void* d_ws, size_t ws_size,
                              hipStream_t stream) {
  const float* x  = (const float*)d_in[0];
  const float* W1 = (const float*)d_in[1];
  const float* U1 = (const float*)d_in[2];
  const float* b1 = (const float*)d_in[3];
  const float* W2 = (const float*)d_in[4];
  const float* U2 = (const float*)d_in[5];
  const float* b2 = (const float*)d_in[6];
  float* out = (float*)d_out;

  short* w1t = (short*)d_ws;        // [256][128] bf16
  short* u1t = w1t + 32768;         // [256][64]
  short* w2t = u1t + 16384;         // [256][64]
  short* u2t = w2t + 16384;         // [256][64]

  hipLaunchKernelGGL(wtrans_all, dim3(256), dim3(128), 0, stream,
                     W1, U1, W2, U2, w1t, u1t, w2t, u2t);
  hipLaunchKernelGGL(lstm_fused, dim3(256), dim3(512), 0, stream,
                     x, w1t, u1t, w2t, u2t, b1, b2, out);
}